// Round 15
// baseline (84.642 us; speedup 1.0000x reference)
//
#include <hip/hip_runtime.h>
#include <math.h>

#define HW 256
#define MINNORM 1.17549435e-38f   // 2^-126, f32 min normal

// One wave (64 lanes) per batch element; lane l owns count-support j = l.
// np ref semantics (verified R4..R14): XLA-CPU f32, FTZ/DAZ, pow underflow at
// j=42 -> support lives in [0,41].
// HARD-WON:
//  R10: flush+renormalize must happen at ref's exact points/scales each step.
//  R11: no cancellation forms for output p_z (S-p2 -> NaN near death).
//  R7/R12/R13/R14: issue-count, scheduling, chain-round halving, and
//   readlane-free reductions ALL NEUTRAL on dur_us — suggesting the kernel is
//   already below the harness's fixed overhead (268MB ws-poison fills at 83%
//   HBM peak dominate the timed stream).
// R15: MEASUREMENT ROUND. R12 kernel (best passing dur_us=69.35) launched
//  TWICE: dur_us - 69.35 = true kernel time k, no model assumptions.
//  Idempotent (same inputs -> same output, written twice); capture-safe.

template <int CTRL>
__device__ __forceinline__ float dpp_sra(float x) {
    // x + (x shifted toward higher lanes within each row of 16); OOB lanes add 0
    int s = __builtin_amdgcn_update_dpp(0, __builtin_bit_cast(int, x),
                                        CTRL, 0xf, 0xf, true);
    return x + __builtin_bit_cast(float, s);
}

__device__ __forceinline__ float rdlane(float x, int l) {
    return __builtin_bit_cast(float,
        __builtin_amdgcn_readlane(__builtin_bit_cast(int, x), l));
}

// Dual wave sum, stages interleaved (chains hide each other's hazard waits).
// Support lives in lanes 0..41; row 3 structurally zero -> dropped (bit-exact).
__device__ __forceinline__ void wave_total2(float x, float y,
                                            float& sx, float& sy) {
    x = dpp_sra<0x111>(x);  y = dpp_sra<0x111>(y);
    x = dpp_sra<0x112>(x);  y = dpp_sra<0x112>(y);
    x = dpp_sra<0x114>(x);  y = dpp_sra<0x114>(y);
    x = dpp_sra<0x118>(x);  y = dpp_sra<0x118>(y);
    const float a0 = rdlane(x, 15), b0 = rdlane(y, 15);
    const float a1 = rdlane(x, 31), b1 = rdlane(y, 31);
    const float a2 = rdlane(x, 47), b2 = rdlane(y, 47);
    sx = (a0 + a1) + a2;
    sy = (b0 + b1) + b2;
}

__global__ void __launch_bounds__(64, 1)
spair_count_kl(const float* __restrict__ z_pres,
               const float* __restrict__ z_prob,
               float* __restrict__ out) {
    // f32 denorm mode = flush in+out (FP_DENORM[1:0]=0), matching XLA FTZ.
    float tok;
    asm volatile("s_setreg_imm32_b32 hwreg(HW_REG_MODE, 4, 2), 0\n\t"
                 "v_mov_b32 %0, 0" : "=v"(tok));

    const int lane = threadIdx.x;   // 0..63
    const int b = blockIdx.x;       // batch element

    // ---- cd0 init (unchanged from passing R4..R12): support cap j=41 ----
    const float e2f = (float)exp(2.0);                    // f32(exp(2))
    const float pf  = (float)(1.0 / ((double)e2f + 1.0)); // p in f32
    const double pd = (double)pf;
    const double l2p = log2(pd);
    float cd = 0.0f;
    if (lane <= 41) {
        const double powj = exp2((double)lane * l2p);      // accurate p^j
        float v = (float)((1.0 - pd) * powj);              // (1-p)*p^j, f32
        cd = (v < MINNORM) ? 0.0f : v;                     // j=41 survives
    }
    {
        float s = cd;
#pragma unroll
        for (int off = 32; off > 0; off >>= 1) s += __shfl_xor(s, off, 64);
        cd = cd / s;
    }
    cd += tok;                 // order the recurrence after the setreg
    const float jf = (float)lane;
    float csf = tok;           // 0.0f, ordered

    // per-lane CR 1/den registers (bit-identical to 1.0f/(float)(HW-i)):
    const float it0 = 1.0f / (float)(HW - lane);
    const float it1 = 1.0f / (float)(HW - 64 - lane);
    const float it2 = 1.0f / (float)(HW - 128 - lane);
    const float it3 = 1.0f / (float)(HW - 192 - lane);

    const float* presb = z_pres + (size_t)b * HW;
    const float* probb = z_prob + (size_t)b * HW;
    float* outb = out + (size_t)b * HW;

    bool dead = false;

#pragma unroll 1
    for (int k = 0; k < 4; ++k) {
        const float myprob = probb[k * 64 + lane];
        const float mypres = presb[k * 64 + lane];
        // sample = round(z_pres) in {0,1}; rintf = round-half-even = np.round
        const unsigned long long smask = __ballot(rintf(mypres) != 0.0f);
        float my_pz = 0.0f;
        const float itk = (k == 0) ? it0 : (k == 1) ? it1 : (k == 2) ? it2 : it3;

        if (!dead) {
#pragma unroll 1
            for (int blk = 0; blk < 4; ++blk) {
                float p2 = 1.0f;   // last-step presum (absorbing-zero sentinel)
#pragma unroll
                for (int u = 0; u < 16; ++u) {
                    const int ii = blk * 16 + u;
                    const int i = k * 64 + ii;
                    const float fden = (float)(HW - i);     // uniform
                    const float inv = rdlane(itk, ii);      // CR 1/den, off-chain
                    const bool s1 = ((smask >> ii) & 1ULL) != 0ULL; // uniform

                    // pg = clip(j-csf,0,den)/den; endpoints exact
                    // (0 via mul, 1 forced — den*inv may not round to 1)
                    const float t = fminf(fmaxf(jf - csf, 0.0f), fden);
                    const float pg = (t == fden) ? 1.0f : t * inv;
                    const float mult = s1 ? pg : (1.0f - pg);  // cndmask

                    // ---- STATE PATH (bit-identical to R9) ----
                    const float prodm = cd * mult;       // HW-FTZ
                    const float p1 = cd * pg;            // HW-FTZ (p_z terms)
                    float p1s;
                    wave_total2(prodm, p1, p2, p1s);     // fused dual reduction
                    const float norm = fmaxf(p2, 1e-6f); // clip(sum,1e-6,∞)
                    const float invn = __builtin_amdgcn_rcpf(norm);
                    cd = prodm * invn;                   // renormalize
                    csf += s1 ? 1.0f : 0.0f;

                    // ---- OUTPUT PATH ----
                    // s1: ref p_z terms == norm terms exactly -> p2.
                    const float pz = s1 ? p2 : p1s;
                    my_pz = (ii == lane) ? pz : my_pz;   // capture step-i p_z
                }
                // Lazy absorbing-death check: any earlier zero keeps p2 at 0.
                if (p2 == 0.0f) { dead = true; break; }
            }
        }

        // KL for this lane's step (i = k*64 + lane); my_pz==0 on dead steps is
        // exactly the ref's p_z=0 closed form.
        const float prob = myprob;
        const float pz = my_pz;
        const float kl = prob * (logf(prob + 1e-9f) - logf(pz + 1e-9f))
                       + (1.0f - prob) * (logf((1.0f - prob) + 1e-9f)
                                        - logf((1.0f - pz) + 1e-9f));
        outb[k * 64 + lane] = kl;   // coalesced across the wave
    }
}

extern "C" void kernel_launch(void* const* d_in, const int* in_sizes, int n_in,
                              void* d_out, int out_size, void* d_ws, size_t ws_size,
                              hipStream_t stream) {
    const float* z_pres = (const float*)d_in[0];      // setup_inputs order
    const float* z_prob = (const float*)d_in[1];
    float* out = (float*)d_out;
    const int nbatch = in_sizes[0] / HW;              // 1024
    // MEASUREMENT: two identical launches. dur_us - 69.35 = true kernel time.
    // Idempotent: second launch recomputes the same output from the same
    // inputs. Same work every call; no sync; capture-safe.
    spair_count_kl<<<dim3(nbatch), dim3(64), 0, stream>>>(z_pres, z_prob, out);
    spair_count_kl<<<dim3(nbatch), dim3(64), 0, stream>>>(z_pres, z_prob, out);
}